// Round 8
// baseline (1480.355 us; speedup 1.0000x reference)
//
#include <hip/hip_runtime.h>
#include <hip/hip_fp16.h>

#define BATCH 32
#define SEQ   1024
#define DIM   512

typedef _Float16 f16x8 __attribute__((ext_vector_type(8)));
typedef float    f32x4 __attribute__((ext_vector_type(4)));
typedef unsigned int u32x4 __attribute__((ext_vector_type(4)));

union UU4 { uint4 s; u32x4 v; };

static __device__ __forceinline__ float tanh_fast(float x) {
    float e = __expf(2.0f * x);
    return 1.0f - 2.0f / (e + 1.0f);
}

// ---------------------------------------------------------------------------
// Pack BOTH 512x512 fp32 row-major W's into fp16 MFMA B-fragment layout in
// one launch (saves a launch gap):
//   Wp[((k>>5)*512 + n)*32 + ((k>>3)&3)*8 + (k&7)] = W[k][n]
// Blocks 0..511 pack W0 -> Wp0, blocks 512..1023 pack W1 -> Wp1.
// ---------------------------------------------------------------------------
__global__ void pack_w2(const float* __restrict__ W0, __half* __restrict__ Wp0,
                        const float* __restrict__ W1, __half* __restrict__ Wp1) {
    int blk = blockIdx.x;
    const float* W  = (blk < 512) ? W0 : W1;
    __half*      Wp = (blk < 512) ? Wp0 : Wp1;
    int id = (blk & 511) * blockDim.x + threadIdx.x;   // 0 .. 262143
    int n = id & 511;
    int k = id >> 9;
    Wp[((k >> 5) * 512 + n) * 32 + ((k >> 3) & 3) * 8 + (k & 7)] = __float2half(W[k * 512 + n]);
}

// ---------------------------------------------------------------------------
// Kernel 1 (v4): xw = x @ W_xh + b. ONE 1024-thread block per CU:
// grid (2, 128), 16 waves x 16 rows = 256 rows x 256 cols per block.
// Rationale: v3 (4 waves/block, 4 arbitrary blocks/CU) gave L1 no cross-wave
// W-reuse window -> ~1 GB of L2 W-traffic (4096 waves x 256 KB). With one
// block/CU, all 16 waves walk the same 16 KB/kb W window in lockstep-ish
// order -> L1 (32 KB) catches the reuse -> W L2 traffic ~64 MB.
// acc[16] f32x4 = 64 VGPRs; launch_bounds(1024,1) caps regs at 128 so all
// 16 waves fit on one CU.
// ---------------------------------------------------------------------------
__global__ __launch_bounds__(1024, 1) void gemm_xw(const float* __restrict__ X,
                                                   const __half* __restrict__ Wp,
                                                   const float* __restrict__ bias,
                                                   float* __restrict__ out) {
    const int nb   = blockIdx.x;          // 0..1   (256-col half)
    const int mb   = blockIdx.y;          // 0..127 (256-row stripe)
    const int lane = threadIdx.x & 63;
    const int wave = threadIdx.x >> 6;    // 0..15
    const int q    = lane >> 4;
    const int r16  = lane & 15;
    const int row  = mb * 256 + wave * 16 + r16;

    const float4* Xf4  = (const float4*)X;
    const uint4*  WpU4 = (const uint4*)Wp;

    f32x4 acc[16];
    #pragma unroll
    for (int nt = 0; nt < 16; ++nt) acc[nt] = (f32x4){0.f, 0.f, 0.f, 0.f};

    #pragma unroll 2
    for (int kb = 0; kb < 16; ++kb) {
        float4 a0 = Xf4[row * 128 + kb * 8 + q * 2];
        float4 a1 = Xf4[row * 128 + kb * 8 + q * 2 + 1];
        f16x8 af;
        af[0] = (_Float16)a0.x; af[1] = (_Float16)a0.y;
        af[2] = (_Float16)a0.z; af[3] = (_Float16)a0.w;
        af[4] = (_Float16)a1.x; af[5] = (_Float16)a1.y;
        af[6] = (_Float16)a1.z; af[7] = (_Float16)a1.w;
        #pragma unroll
        for (int nt = 0; nt < 16; ++nt) {
            int col = nb * 256 + nt * 16 + r16;
            UU4 tmp; tmp.s = WpU4[(kb * 512 + col) * 4 + q];
            acc[nt] = __builtin_amdgcn_mfma_f32_16x16x32_f16(
                af, __builtin_bit_cast(f16x8, tmp.v), acc[nt], 0, 0, 0);
        }
    }

    const int rbase = mb * 256 + wave * 16 + q * 4;
    #pragma unroll
    for (int nt = 0; nt < 16; ++nt) {
        int col = nb * 256 + nt * 16 + r16;
        float bv = bias[col];
        #pragma unroll
        for (int rr = 0; rr < 4; ++rr) {
            out[(size_t)(rbase + rr) * 512 + col] = acc[nt][rr] + bv;
        }
    }
}

// ---------------------------------------------------------------------------
// Kernel 2: recurrence — VERBATIM the R1-v2 kernel (harness-verified,
// 1310 us). AT ITS DESIGN ROOFLINE: per step per CU the LDS pipe issues
// ~264 b128-class wave-instrs x ~12 cyc ~= 3100 cyc = the measured 3071-cyc
// step, with the MFMA floor (512 x 4.85 = 2483 cyc) just beneath. Full W
// register-residency would need 2048 regs/CU (the entire unified RF), so
// the 48-AGPR + 16-LDS-streamed split is the capacity optimum; af-read
// count is invariant under wave-count reshuffles. Do not touch.
// ---------------------------------------------------------------------------
__global__ __launch_bounds__(512, 2) void rnn_rec(const uint4* __restrict__ Wp4,
                                                  float* __restrict__ out) {
    extern __shared__ char smem[];
    uint4*  LBS = (uint4*)smem;                 // 8192 uint4 = 128 KB (kb 12..15)
    __half* hb  = (__half*)(smem + 131072);     // 2 x 512 halves (double buffer)

    const int b    = blockIdx.x;
    const int t    = threadIdx.x;    // 0..511
    const int lane = t & 63;
    const int w    = t >> 6;         // wave 0..7: owns cols [w*64, w*64+64)
    const int q    = lane >> 4;      // quad 0..3 (== this thread's N-tile)
    const int r16  = lane & 15;

    // Stage streamed B-fragments (k-blocks 12..15) into LDS.
    #pragma unroll
    for (int j = 0; j < 16; ++j) {
        int kb  = 12 + (j >> 2);
        int col = w * 64 + (j & 3) * 16 + r16;
        LBS[j * 512 + t] = Wp4[(kb * 512 + col) * 4 + q];
    }

    // Resident B-fragments: k-blocks 0..11 x 4 N-tiles = 48 uint4 / lane,
    // pinned to AGPRs (the ONLY pin budget proven correct here).
    u32x4 Bf[48];
    #pragma unroll
    for (int kb = 0; kb < 12; ++kb) {
        #pragma unroll
        for (int nt = 0; nt < 4; ++nt) {
            int col = w * 64 + nt * 16 + r16;
            UU4 tmp; tmp.s = Wp4[(kb * 512 + col) * 4 + q];
            Bf[kb * 4 + nt] = tmp.v;
        }
    }
    #pragma unroll
    for (int i = 0; i < 48; ++i) asm volatile("" : "+a"(Bf[i]));

    float* orow = out + (size_t)b * SEQ * DIM;
    const int c = w * 64 + q * 16 + r16;   // this thread's single output col

    // Step 0: h = tanh(xw).
    float xw = orow[c];
    float h  = tanh_fast(xw);
    orow[c] = h;
    hb[c] = __float2half(h);
    xw = orow[DIM + c];                    // prefetch step 1's xw
    __syncthreads();

    #pragma unroll 1
    for (int step = 1; step < SEQ; ++step) {
        orow += DIM;
        const __half* ha = hb + (((step & 1) ^ 1) << 9);   // h_{t-1}

        f32x4 m[4];
        #pragma unroll
        for (int i = 0; i < 4; ++i) m[i] = (f32x4){0.f, 0.f, 0.f, 0.f};

        // Streamed k-blocks first (LDS reads fill the pipe while MFMAs start).
        #pragma unroll
        for (int s = 0; s < 4; ++s) {
            f16x8 af = *(const f16x8*)(ha + (12 + s) * 32 + q * 8);
            #pragma unroll
            for (int nt = 0; nt < 4; ++nt) {
                UU4 tmp; tmp.s = LBS[(s * 4 + nt) * 512 + t];
                m[nt] = __builtin_amdgcn_mfma_f32_16x16x32_f16(
                    af, __builtin_bit_cast(f16x8, tmp.v), m[nt], 0, 0, 0);
            }
        }
        // Resident k-blocks.
        #pragma unroll
        for (int kb = 0; kb < 12; ++kb) {
            f16x8 af = *(const f16x8*)(ha + kb * 32 + q * 8);
            #pragma unroll
            for (int nt = 0; nt < 4; ++nt) {
                m[nt] = __builtin_amdgcn_mfma_f32_16x16x32_f16(
                    af, __builtin_bit_cast(f16x8, Bf[kb * 4 + nt]), m[nt], 0, 0, 0);
            }
        }

        // All acc rows equal (replicated A): tile q, reg 0 holds col c.
        float v = (q == 0 ? m[0][0] : q == 1 ? m[1][0] : q == 2 ? m[2][0] : m[3][0]) + xw;
        h = tanh_fast(v);

        orow[c] = h;
        __half* hw = hb + ((step & 1) << 9);
        hw[c] = __float2half(h);
        // Prefetch next xw (step 1023 reads into the h_final region: in-bounds,
        // value unused).
        xw = orow[DIM + c];
        __syncthreads();
    }

    float* hf = out + (size_t)BATCH * SEQ * DIM + (size_t)b * DIM;
    hf[c] = h;
}

extern "C" void kernel_launch(void* const* d_in, const int* in_sizes, int n_in,
                              void* d_out, int out_size, void* d_ws, size_t ws_size,
                              hipStream_t stream) {
    const float* X    = (const float*)d_in[0];   // [32,1024,512] fp32
    const float* Wxh  = (const float*)d_in[1];   // [512,512] fp32
    const float* Whh  = (const float*)d_in[2];   // [512,512] fp32
    const float* bias = (const float*)d_in[3];   // [512] fp32
    float* out = (float*)d_out;

    __half* WpXh = (__half*)d_ws;                          // 512 KB @ 0
    __half* WpHh = (__half*)((char*)d_ws + (512u << 10));  // 512 KB @ 512K

    (void)hipFuncSetAttribute((const void*)rnn_rec,
                              hipFuncAttributeMaxDynamicSharedMemorySize, 133120);

    pack_w2<<<1024, 512, 0, stream>>>(Wxh, WpXh, Whh, WpHh);
    gemm_xw<<<dim3(2, 128), 1024, 0, stream>>>(X, WpXh, bias, out);
    rnn_rec<<<BATCH, 512, 133120, stream>>>((const uint4*)WpHh, out);
}

// Round 9
// 1439.271 us; speedup vs baseline: 1.0285x; 1.0285x over previous
//
#include <hip/hip_runtime.h>
#include <hip/hip_fp16.h>

#define BATCH 32
#define SEQ   1024
#define DIM   512

typedef _Float16 f16x8 __attribute__((ext_vector_type(8)));
typedef float    f32x4 __attribute__((ext_vector_type(4)));
typedef unsigned int u32x4 __attribute__((ext_vector_type(4)));

union UU4 { uint4 s; u32x4 v; };

static __device__ __forceinline__ float tanh_fast(float x) {
    float e = __expf(2.0f * x);
    return 1.0f - 2.0f / (e + 1.0f);
}

// Consumer gate: wait until both col-halves of (batch,stripe) xw are published.
// Device-scope acquire pairs with the producer's threadfence+release-add;
// first touch of the stripe's cache lines happens strictly after the acquire.
static __device__ __forceinline__ void gate_wait(unsigned int* flags, int idx) {
    if (threadIdx.x == 0) {
        while (__hip_atomic_load(&flags[idx], __ATOMIC_ACQUIRE,
                                 __HIP_MEMORY_SCOPE_AGENT) < 2u)
            __builtin_amdgcn_s_sleep(8);
    }
    __syncthreads();
}

// ---------------------------------------------------------------------------
// Pack BOTH W's into fp16 MFMA B-fragment layout, and zero the 256 progress
// flags (runs before the fused kernel every iteration; kernel boundary makes
// the zeroing visible):
//   Wp[((k>>5)*512 + n)*32 + ((k>>3)&3)*8 + (k&7)] = W[k][n]
// ---------------------------------------------------------------------------
__global__ void pack_w2(const float* __restrict__ W0, __half* __restrict__ Wp0,
                        const float* __restrict__ W1, __half* __restrict__ Wp1,
                        unsigned int* __restrict__ flags) {
    if (blockIdx.x == 0 && threadIdx.x < 256) flags[threadIdx.x] = 0u;
    int blk = blockIdx.x;
    const float* W  = (blk < 512) ? W0 : W1;
    __half*      Wp = (blk < 512) ? Wp0 : Wp1;
    int id = (blk & 511) * blockDim.x + threadIdx.x;   // 0 .. 262143
    int n = id & 511;
    int k = id >> 9;
    Wp[((k >> 5) * 512 + n) * 32 + ((k >> 3) & 3) * 8 + (k & 7)] = __float2half(W[k * 512 + n]);
}

// ---------------------------------------------------------------------------
// FUSED kernel, 544 blocks x 512 threads.
//   blocks 0..31   : rnn consumer (proven R1-v2 body + 8 per-stripe gates)
//   blocks 32..543 : xw producer (proven gemm-v3 body, 8-wave variant:
//                    128 rows x 256 cols). Producer order sg = stripe*32 +
//                    batch -> stripe 0 of EVERY batch is produced in the
//                    first dispatch round, so rnn blocks start within ~10 us.
// Producer stays ~40x ahead of consumption (stripe: ~10 us to produce vs
// 164 us to consume). <=32 spinners vs 224+ free CUs: deadlock-free.
// Flags are grow-only latches (>=2 test): rocprof replay benign.
// ---------------------------------------------------------------------------
__global__ __launch_bounds__(512, 2) void fused_rnn(
        const float* __restrict__ X, const __half* __restrict__ WpXh,
        const float* __restrict__ bias, const uint4* __restrict__ WpHh4,
        float* __restrict__ out, unsigned int* __restrict__ flags)
{
    extern __shared__ char smem[];
    const int lane = threadIdx.x & 63;
    const int w    = threadIdx.x >> 6;   // wave 0..7
    const int q    = lane >> 4;          // quad 0..3
    const int r16  = lane & 15;

    if (blockIdx.x >= 32) {
        // ------------------- PRODUCER: xw = x @ W_xh + b -------------------
        const int g  = (int)blockIdx.x - 32;   // 0..511
        const int nb = g & 1;                  // col half
        const int sg = g >> 1;                 // 0..255 = stripe*32 + batch
        const int bg = sg & 31;                // batch
        const int st = sg >> 5;                // stripe (128 timesteps)
        const int row = bg * 1024 + st * 128 + w * 16 + r16;

        const float4* Xf4  = (const float4*)X;
        const uint4*  WpU4 = (const uint4*)WpXh;

        f32x4 acc[16];
        #pragma unroll
        for (int nt = 0; nt < 16; ++nt) acc[nt] = (f32x4){0.f, 0.f, 0.f, 0.f};

        #pragma unroll 2
        for (int kb = 0; kb < 16; ++kb) {
            float4 a0 = Xf4[row * 128 + kb * 8 + q * 2];
            float4 a1 = Xf4[row * 128 + kb * 8 + q * 2 + 1];
            f16x8 af;
            af[0] = (_Float16)a0.x; af[1] = (_Float16)a0.y;
            af[2] = (_Float16)a0.z; af[3] = (_Float16)a0.w;
            af[4] = (_Float16)a1.x; af[5] = (_Float16)a1.y;
            af[6] = (_Float16)a1.z; af[7] = (_Float16)a1.w;
            #pragma unroll
            for (int nt = 0; nt < 16; ++nt) {
                int col = nb * 256 + nt * 16 + r16;
                UU4 tmp; tmp.s = WpU4[(kb * 512 + col) * 4 + q];
                acc[nt] = __builtin_amdgcn_mfma_f32_16x16x32_f16(
                    af, __builtin_bit_cast(f16x8, tmp.v), acc[nt], 0, 0, 0);
            }
        }

        const int rbase = bg * 1024 + st * 128 + w * 16 + q * 4;
        #pragma unroll
        for (int nt = 0; nt < 16; ++nt) {
            int col = nb * 256 + nt * 16 + r16;
            float bv = bias[col];
            #pragma unroll
            for (int rr = 0; rr < 4; ++rr) {
                out[(size_t)(rbase + rr) * 512 + col] = acc[nt][rr] + bv;
            }
        }

        // Publish: __syncthreads drains each wave's stores; threadfence
        // flushes them to the device coherence point; release-add signals.
        __syncthreads();
        if (threadIdx.x == 0) {
            __threadfence();
            __hip_atomic_fetch_add(&flags[sg], 1u, __ATOMIC_RELEASE,
                                   __HIP_MEMORY_SCOPE_AGENT);
        }
        return;
    }

    // ---------------------- CONSUMER: recurrence ----------------------
    // Proven R1-v2 body (1310 us). Only delta: 8 uniform per-stripe gates
    // placed BEFORE the xw prefetch crosses into a new 128-step stripe.
    uint4*  LBS = (uint4*)smem;                 // 8192 uint4 = 128 KB (kb 12..15)
    __half* hb  = (__half*)(smem + 131072);     // 2 x 512 halves (double buffer)

    const int b = blockIdx.x;
    const int t = threadIdx.x;    // 0..511

    // Stage streamed B-fragments (k-blocks 12..15) into LDS.
    #pragma unroll
    for (int j = 0; j < 16; ++j) {
        int kb  = 12 + (j >> 2);
        int col = w * 64 + (j & 3) * 16 + r16;
        LBS[j * 512 + t] = WpHh4[(kb * 512 + col) * 4 + q];
    }

    // Resident B-fragments: k-blocks 0..11 x 4 N-tiles = 48 uint4 / lane,
    // pinned to AGPRs (the ONLY pin budget proven correct here).
    u32x4 Bf[48];
    #pragma unroll
    for (int kb = 0; kb < 12; ++kb) {
        #pragma unroll
        for (int nt = 0; nt < 4; ++nt) {
            int col = w * 64 + nt * 16 + r16;
            UU4 tmp; tmp.s = WpHh4[(kb * 512 + col) * 4 + q];
            Bf[kb * 4 + nt] = tmp.v;
        }
    }
    #pragma unroll
    for (int i = 0; i < 48; ++i) asm volatile("" : "+a"(Bf[i]));

    float* orow = out + (size_t)b * SEQ * DIM;
    const int c = w * 64 + q * 16 + r16;   // this thread's single output col

    // Wait for stripe 0 of this batch (rows 0..127), then step 0.
    gate_wait(flags, 0 * 32 + b);

    float xw = orow[c];
    float h  = tanh_fast(xw);
    orow[c] = h;
    hb[c] = __float2half(h);
    xw = orow[DIM + c];                    // prefetch step 1's xw (stripe 0)
    __syncthreads();

    #pragma unroll 1
    for (int step = 1; step < SEQ; ++step) {
        orow += DIM;
        const __half* ha = hb + (((step & 1) ^ 1) << 9);   // h_{t-1}

        f32x4 m[4];
        #pragma unroll
        for (int i = 0; i < 4; ++i) m[i] = (f32x4){0.f, 0.f, 0.f, 0.f};

        // Streamed k-blocks first (LDS reads fill the pipe while MFMAs start).
        #pragma unroll
        for (int s = 0; s < 4; ++s) {
            f16x8 af = *(const f16x8*)(ha + (12 + s) * 32 + q * 8);
            #pragma unroll
            for (int nt = 0; nt < 4; ++nt) {
                UU4 tmp; tmp.s = LBS[(s * 4 + nt) * 512 + t];
                m[nt] = __builtin_amdgcn_mfma_f32_16x16x32_f16(
                    af, __builtin_bit_cast(f16x8, tmp.v), m[nt], 0, 0, 0);
            }
        }
        // Resident k-blocks.
        #pragma unroll
        for (int kb = 0; kb < 12; ++kb) {
            f16x8 af = *(const f16x8*)(ha + kb * 32 + q * 8);
            #pragma unroll
            for (int nt = 0; nt < 4; ++nt) {
                m[nt] = __builtin_amdgcn_mfma_f32_16x16x32_f16(
                    af, __builtin_bit_cast(f16x8, Bf[kb * 4 + nt]), m[nt], 0, 0, 0);
            }
        }

        // All acc rows equal (replicated A): tile q, reg 0 holds col c.
        float v = (q == 0 ? m[0][0] : q == 1 ? m[1][0] : q == 2 ? m[2][0] : m[3][0]) + xw;
        h = tanh_fast(v);

        orow[c] = h;
        __half* hw = hb + ((step & 1) << 9);
        hw[c] = __float2half(h);

        // Gate before the prefetch crosses into a new 128-step stripe.
        // (step+1 == SEQ would index stripe 8: excluded; that final prefetch
        // reads the next batch's row 0 / h_final region — value unused.)
        const int nstep = step + 1;
        if ((nstep & 127) == 0 && nstep < SEQ)
            gate_wait(flags, (nstep >> 7) * 32 + b);

        xw = orow[DIM + c];
        __syncthreads();
    }

    float* hf = out + (size_t)BATCH * SEQ * DIM + (size_t)b * DIM;
    hf[c] = h;
}

extern "C" void kernel_launch(void* const* d_in, const int* in_sizes, int n_in,
                              void* d_out, int out_size, void* d_ws, size_t ws_size,
                              hipStream_t stream) {
    const float* X    = (const float*)d_in[0];   // [32,1024,512] fp32
    const float* Wxh  = (const float*)d_in[1];   // [512,512] fp32
    const float* Whh  = (const float*)d_in[2];   // [512,512] fp32
    const float* bias = (const float*)d_in[3];   // [512] fp32
    float* out = (float*)d_out;

    __half* WpXh = (__half*)d_ws;                                  // 512 KB @ 0
    __half* WpHh = (__half*)((char*)d_ws + (512u << 10));          // 512 KB @ 512K
    unsigned int* flags = (unsigned int*)((char*)d_ws + (1024u << 10)); // 1 KB @ 1M

    (void)hipFuncSetAttribute((const void*)fused_rnn,
                              hipFuncAttributeMaxDynamicSharedMemorySize, 133120);

    pack_w2<<<1024, 512, 0, stream>>>(Wxh, WpXh, Whh, WpHh, flags);
    fused_rnn<<<544, 512, 133120, stream>>>(X, WpXh, bias,
                                            (const uint4*)WpHh, out, flags);
}